// Round 6
// baseline (884.994 us; speedup 1.0000x reference)
//
#include <hip/hip_runtime.h>
#include <hip/hip_bf16.h>
#include <stdint.h>

#define BTOT  65536
#define KTR   11
#define NSLOT 12   // 11 transforms + z

typedef __attribute__((ext_vector_type(8))) short bf16x8_t;
typedef __attribute__((ext_vector_type(4))) float f32x4_t;

// Swizzled LDS layout: row m x 256 bf16 cols, 16B groups rotated by row so
// frag ds_read_b128 across 16 rows spreads banks (<=2-way, free per m136).
__device__ __forceinline__ int act_addr(int m, int n) {
    return m * 256 + ((((n >> 3) + m) & 31) << 3) + (n & 7);
}

// tanh-form gelu, exp2-native: log2(e) folded into the 1.59576912 constant.
__device__ __forceinline__ float gelu_fast(float x) {
    float x2 = x * x;
    float t2 = 2.3022083f * x * fmaf(0.044715f, x2, 1.0f);   // 1.5957691*log2e
    float e  = exp2f(fminf(t2, 44.f));
    return x * e * __builtin_amdgcn_rcpf(1.0f + e);
}

// generic fp32 -> bf16 cast, 4 elems/thread (also used for Tw2 cast)
__global__ void cast_x_kernel(const float* __restrict__ x, __hip_bfloat16* __restrict__ xb) {
    int i = (blockIdx.x * 256 + threadIdx.x) * 4;
    float4 v = *(const float4*)(x + i);
    union { __hip_bfloat16 h[4]; uint64_t u; } o;
    o.h[0] = __float2bfloat16(v.x);
    o.h[1] = __float2bfloat16(v.y);
    o.h[2] = __float2bfloat16(v.z);
    o.h[3] = __float2bfloat16(v.w);
    *(uint64_t*)(xb + i) = o.u;
}

// out[b][c][r] = in[b][r][c], cast fp32 -> bf16.
__global__ void transpose_cast_kernel(const float* __restrict__ in,
                                      __hip_bfloat16* __restrict__ out,
                                      int R, int C) {
    __shared__ float tile[32][33];
    int tpc = C >> 5;
    int tr = (blockIdx.x / tpc) << 5;
    int tc = (blockIdx.x % tpc) << 5;
    const float* bi = in + (size_t)blockIdx.y * R * C;
    __hip_bfloat16* bo = out + (size_t)blockIdx.y * R * C;
    int lx = threadIdx.x & 31, ly = threadIdx.x >> 5;
    #pragma unroll
    for (int r = 0; r < 32; r += 8)
        tile[ly + r][lx] = bi[(size_t)(tr + ly + r) * C + tc + lx];
    __syncthreads();
    #pragma unroll
    for (int r = 0; r < 32; r += 8)
        bo[(size_t)(tc + ly + r) * R + tr + lx] = __float2bfloat16(tile[lx][ly + r]);
}

// Fused weight: Wft[k][j][h] = sum_d Ew1t[j][d] * Tw2b[k][h][d]
// (= (Tw2[k] @ Ew1)^T). Legal: no nonlinearity between Tw2 and Ew1 stages.
__global__ void fuse_w_kernel(const __hip_bfloat16* __restrict__ Ew1t,
                              const __hip_bfloat16* __restrict__ Tw2b,
                              __hip_bfloat16* __restrict__ Wft)
{
    __shared__ __align__(16) __hip_bfloat16 bt[64 * 256];
    const int tid  = threadIdx.x;
    const int wave = tid >> 6, lane = tid & 63;
    const int lr = lane & 15, q = lane >> 4;
    const int k  = blockIdx.y;
    const int h0 = blockIdx.x << 6;
    const __hip_bfloat16* src = Tw2b + (size_t)k * 65536;

    #pragma unroll
    for (int i = 0; i < 8; ++i) {
        int lin = i * 256 + tid;
        int r = lin >> 5, g = lin & 31;
        bf16x8_t v = *(const bf16x8_t*)(src + (size_t)(h0 + r) * 256 + g * 8);
        *(bf16x8_t*)(bt + act_addr(r, g * 8)) = v;
    }
    __syncthreads();

    const int wc = wave << 6;
    f32x4_t acc[4][4];
    #pragma unroll
    for (int mt = 0; mt < 4; ++mt)
        #pragma unroll
        for (int nt = 0; nt < 4; ++nt)
            acc[mt][nt] = (f32x4_t){0.f, 0.f, 0.f, 0.f};

    #pragma unroll 1
    for (int kc = 0; kc < 8; ++kc) {
        const int kof = (kc << 5) + (q << 3);
        bf16x8_t a[4], b[4];
        #pragma unroll
        for (int mt = 0; mt < 4; ++mt)
            a[mt] = *(const bf16x8_t*)(Ew1t + (size_t)(wc + (mt << 4) + lr) * 256 + kof);
        #pragma unroll
        for (int nt = 0; nt < 4; ++nt)
            b[nt] = *(const bf16x8_t*)(bt + act_addr((nt << 4) + lr, kof));
        #pragma unroll
        for (int mt = 0; mt < 4; ++mt)
            #pragma unroll
            for (int nt = 0; nt < 4; ++nt)
                acc[mt][nt] = __builtin_amdgcn_mfma_f32_16x16x32_bf16(a[mt], b[nt], acc[mt][nt], 0, 0, 0);
    }

    __hip_bfloat16* dst = Wft + (size_t)k * 65536;
    #pragma unroll
    for (int mt = 0; mt < 4; ++mt)
        #pragma unroll
        for (int nt = 0; nt < 4; ++nt) {
            const int h = h0 + (nt << 4) + lr;
            #pragma unroll
            for (int r = 0; r < 4; ++r) {
                const int j = wc + (mt << 4) + (q << 2) + r;
                dst[(size_t)j * 256 + h] = __float2bfloat16(acc[mt][nt][r]);
            }
        }
}

// bf[k][j] = Eb1[j] + sum_d Tb2[k][d] * Ew1[d][j]   (fp32 throughout)
__global__ void fuse_b_kernel(const float* __restrict__ Tb2,
                              const float* __restrict__ Ew1,
                              const float* __restrict__ Eb1,
                              float* __restrict__ bf)
{
    const int k = blockIdx.x, j = threadIdx.x;
    float s = Eb1[j];
    #pragma unroll 4
    for (int d = 0; d < 256; ++d)
        s = fmaf(Tb2[k * 256 + d], Ew1[d * 256 + j], s);
    bf[k * 256 + j] = s;
}

// One stage: act[64][256] (LDS, swizzled) <- f(act @ W + bias).
// Bias folded into MFMA C-init; DO_GELU templated.
template<bool DO_GELU>
__device__ void run_stage(__hip_bfloat16* act,
                          const __hip_bfloat16* __restrict__ Wt,   // [n][k] row-major
                          const float* __restrict__ bias,
                          int wave, int lane)
{
    const int lr = lane & 15;
    const int q  = lane >> 4;
    const int wc = wave << 6;           // weight-col strip base

    f32x4_t acc[4][4];
    #pragma unroll
    for (int mt = 0; mt < 4; ++mt) {
        const float4 bv = *(const float4*)(bias + wc + (mt << 4) + (q << 2));
        #pragma unroll
        for (int nt = 0; nt < 4; ++nt)
            acc[mt][nt] = (f32x4_t){bv.x, bv.y, bv.z, bv.w};
    }

    bf16x8_t a[4];
    #pragma unroll
    for (int mt = 0; mt < 4; ++mt)
        a[mt] = *(const bf16x8_t*)(Wt + (size_t)(wc + (mt << 4) + lr) * 256 + (q << 3));

    #pragma unroll 1
    for (int kc = 0; kc < 8; ++kc) {
        const int kof = (kc << 5) + (q << 3);
        bf16x8_t an[4];
        if (kc < 7) {
            #pragma unroll
            for (int mt = 0; mt < 4; ++mt)
                an[mt] = *(const bf16x8_t*)(Wt + (size_t)(wc + (mt << 4) + lr) * 256 + kof + 32);
        }
        bf16x8_t b[4];
        #pragma unroll
        for (int nt = 0; nt < 4; ++nt)
            b[nt] = *(const bf16x8_t*)(act + act_addr((nt << 4) + lr, kof));
        #pragma unroll
        for (int mt = 0; mt < 4; ++mt)
            #pragma unroll
            for (int nt = 0; nt < 4; ++nt)
                acc[mt][nt] = __builtin_amdgcn_mfma_f32_16x16x32_bf16(a[mt], b[nt], acc[mt][nt], 0, 0, 0);
        if (kc < 7) {
            #pragma unroll
            for (int mt = 0; mt < 4; ++mt) a[mt] = an[mt];
        }
    }

    __syncthreads();   // all waves done reading act before overwrite
    #pragma unroll
    for (int mt = 0; mt < 4; ++mt) {
        const int nbase = wc + (mt << 4) + (q << 2);
        #pragma unroll
        for (int nt = 0; nt < 4; ++nt) {
            const int row = (nt << 4) + lr;
            union { __hip_bfloat16 h[4]; uint64_t u; } o;
            #pragma unroll
            for (int r = 0; r < 4; ++r) {
                float v = acc[mt][nt][r];
                if (DO_GELU) v = gelu_fast(v);
                o.h[r] = __float2bfloat16(v);
            }
            *(uint64_t*)(act + act_addr(row, nbase)) = o.u;
        }
    }
    __syncthreads();
}

// 1D grid, XCD-chunked tile-major swizzle: lid = (bid&7)*(nwg/8) + bid>>3
// puts a CONTIGUOUS run of logical ids (tile-major: lid = tile*12+slot) on
// each XCD -> all 12 slots of a tile share one XCD's L2 -> xb's 64-row tile
// (32KB) is fetched from HBM once instead of ~12x (FETCH was 274MB, ideal
// ~38MB). Requires nwg%8==0 (ntiles even -- guaranteed by chunk%128==0).
__launch_bounds__(256, 3)
__global__ void chain_kernel(const __hip_bfloat16* __restrict__ xb,
                             const __hip_bfloat16* __restrict__ Tw1t,
                             const float* __restrict__ Tb1,
                             const __hip_bfloat16* __restrict__ Wft,
                             const float* __restrict__ bfb,
                             const __hip_bfloat16* __restrict__ Ew1t,
                             const float* __restrict__ Eb1,
                             const __hip_bfloat16* __restrict__ Ew2t,
                             const float* __restrict__ Eb2,
                             __hip_bfloat16* __restrict__ zbuf,
                             int b0)
{
    __shared__ __align__(16) __hip_bfloat16 act[64 * 256];   // 32 KB
    const int tid  = threadIdx.x;
    const int wave = tid >> 6, lane = tid & 63;

    const int nwg  = gridDim.x;
    const int bid  = blockIdx.x;
    const int lid  = (bid & 7) * (nwg >> 3) + (bid >> 3);
    const int tile = lid / NSLOT;
    const int slot = lid - tile * NSLOT;

    // stage x tile (64 rows) into LDS
    #pragma unroll
    for (int i = 0; i < 8; ++i) {
        int lin = i * 256 + tid;
        int r = lin >> 5, g = lin & 31;
        bf16x8_t v = *(const bf16x8_t*)(xb + (size_t)(b0 + tile * 64 + r) * 256 + g * 8);
        *(bf16x8_t*)(act + act_addr(r, g * 8)) = v;
    }
    __syncthreads();

    if (slot < KTR) {
        // T-slot: gelu(x@Tw1+b1) -> gelu(. @ Wf + bf) -> . @ Ew2 + e2
        run_stage<true>(act, Tw1t + (size_t)slot * 65536, Tb1 + slot * 256, wave, lane);
        run_stage<true>(act, Wft  + (size_t)slot * 65536, bfb + slot * 256, wave, lane);
    } else {
        // z-slot: gelu(x@Ew1+e1) -> . @ Ew2 + e2
        run_stage<true>(act, Ew1t, Eb1, wave, lane);
    }
    run_stage<false>(act, Ew2t, Eb2, wave, lane);

    // interleaved zbuf: [row][slot][256]
    __hip_bfloat16* dst = zbuf + ((size_t)(tile * 64) * NSLOT + slot) * 256;
    #pragma unroll
    for (int i = 0; i < 8; ++i) {
        int lin = i * 256 + tid;
        int r = lin >> 5, g = lin & 31;
        bf16x8_t v = *(const bf16x8_t*)(act + act_addr(r, g * 8));
        *(bf16x8_t*)(dst + (size_t)r * NSLOT * 256 + g * 8) = v;
    }
}

// Per row: G = Z Z^T (12x12 over H=256) via mfma(v,v,acc). Byte-identical to
// the R5 version (8 rows/wave, 2-deep row pipeline, rcp-for-divide) so its
// counters, once visible in top-5 via the 2-chunk split, attribute cleanly.
#define ROW_BODY(V, I)                                                        \
    {                                                                         \
        f32x4_t acc = (f32x4_t){0.f, 0.f, 0.f, 0.f};                          \
        _Pragma("unroll")                                                     \
        for (int kc = 0; kc < 8; ++kc)                                        \
            acc = __builtin_amdgcn_mfma_f32_16x16x32_bf16(V[kc], V[kc], acc, 0, 0, 0); \
        _Pragma("unroll")                                                     \
        for (int rr = 0; rr < 4; ++rr)                                        \
            Gw[wave][(q << 2) + rr][lr] = acc[rr];                            \
        float term = 0.f;                                                     \
        if (lane < 11) {                                                      \
            const int k = lane;                                               \
            float nr[NSLOT];                                                  \
            _Pragma("unroll")                                                 \
            for (int l = 0; l < NSLOT; ++l)                                   \
                nr[l] = __builtin_amdgcn_rcpf(fmaxf(sqrtf(Gw[wave][l][l]), 1e-4f)); \
            const float nrk = nr[k];                                          \
            float neg = 0.f;                                                  \
            _Pragma("unroll")                                                 \
            for (int l = 0; l < KTR; ++l)                                     \
                if (l != k)                                                   \
                    neg += __expf(Gw[wave][l][k] * nr[l] * nrk);              \
            float cz = Gw[wave][KTR][k] * nr[KTR] * nrk;                      \
            term = __logf(__expf(cz) + neg) - cz;                             \
        }                                                                     \
        term += __shfl_xor(term, 1);                                          \
        term += __shfl_xor(term, 2);                                          \
        term += __shfl_xor(term, 4);                                          \
        term += __shfl_xor(term, 8);                                          \
        if (lane == 0) out[b0 + r0 + (I)] = term;                             \
    }

__launch_bounds__(256, 4)
__global__ void reduce_kernel(const __hip_bfloat16* __restrict__ zbuf,
                              float* __restrict__ out, int b0)
{
    __shared__ float Gw[4][16][17];
    const int tid  = threadIdx.x;
    const int wave = tid >> 6, lane = tid & 63;
    const int lr = lane & 15, q = lane >> 4;
    const int slot = lr < NSLOT ? lr : NSLOT - 1;   // lanes 12-15 broadcast slot 11
    const size_t lanoff = (size_t)slot * 256 + (q << 3);

    const int r0 = (blockIdx.x * 4 + wave) * 8;     // 8 contiguous rows per wave
    const __hip_bfloat16* zr = zbuf + (size_t)r0 * (NSLOT * 256) + lanoff;

    bf16x8_t va[8], vb[8];
    #pragma unroll
    for (int kc = 0; kc < 8; ++kc)
        va[kc] = *(const bf16x8_t*)(zr + kc * 32);

    #pragma unroll 1
    for (int i2 = 0; i2 < 4; ++i2) {
        const int ie = i2 * 2;
        {   // even row: consume va, prefetch row ie+1 into vb (always valid)
            const __hip_bfloat16* zn = zr + (size_t)(ie + 1) * (NSLOT * 256);
            #pragma unroll
            for (int kc = 0; kc < 8; ++kc)
                vb[kc] = *(const bf16x8_t*)(zn + kc * 32);
            ROW_BODY(va, ie)
        }
        {   // odd row: consume vb, prefetch row ie+2 into va (guarded)
            if (ie + 2 < 8) {
                const __hip_bfloat16* zn = zr + (size_t)(ie + 2) * (NSLOT * 256);
                #pragma unroll
                for (int kc = 0; kc < 8; ++kc)
                    va[kc] = *(const bf16x8_t*)(zn + kc * 32);
            }
            ROW_BODY(vb, ie + 1)
        }
    }
}

extern "C" void kernel_launch(void* const* d_in, const int* in_sizes, int n_in,
                              void* d_out, int out_size, void* d_ws, size_t ws_size,
                              hipStream_t stream)
{
    const float* x   = (const float*)d_in[0];
    const float* Tw1 = (const float*)d_in[1];
    const float* Tb1 = (const float*)d_in[2];
    const float* Tw2 = (const float*)d_in[3];
    const float* Tb2 = (const float*)d_in[4];
    const float* Ew1 = (const float*)d_in[5];
    const float* Eb1 = (const float*)d_in[6];
    const float* Ew2 = (const float*)d_in[7];
    const float* Eb2 = (const float*)d_in[8];
    float* out = (float*)d_out;

    char* ws = (char*)d_ws;
    const size_t off_xb   = 0;
    const size_t off_tw1  = off_xb   + (size_t)BTOT * 256 * 2;     // 32 MB
    const size_t off_wf   = off_tw1  + (size_t)KTR * 65536 * 2;
    const size_t off_ew1  = off_wf   + (size_t)KTR * 65536 * 2;
    const size_t off_ew2  = off_ew1  + (size_t)65536 * 2;
    const size_t off_tw2b = off_ew2  + (size_t)65536 * 2;
    const size_t off_bf   = off_tw2b + (size_t)KTR * 65536 * 2;
    const size_t off_z    = off_bf   + (size_t)KTR * 256 * 4;

    __hip_bfloat16* xb   = (__hip_bfloat16*)(ws + off_xb);
    __hip_bfloat16* Tw1t = (__hip_bfloat16*)(ws + off_tw1);
    __hip_bfloat16* Wft  = (__hip_bfloat16*)(ws + off_wf);
    __hip_bfloat16* Ew1t = (__hip_bfloat16*)(ws + off_ew1);
    __hip_bfloat16* Ew2t = (__hip_bfloat16*)(ws + off_ew2);
    __hip_bfloat16* Tw2b = (__hip_bfloat16*)(ws + off_tw2b);
    float*          bfb  = (float*)(ws + off_bf);
    __hip_bfloat16* zbuf = (__hip_bfloat16*)(ws + off_z);

    // 2-chunk split: halves chain's dispatch duration so reduce (if it is the
    // hidden ~460us consumer) must surface in rocprof's top-5 with counters.
    long long zbytes = (long long)ws_size - (long long)off_z;
    long long rows_cap = zbytes > 0 ? zbytes / ((long long)NSLOT * 256 * 2) : 0;
    int chunk = (int)((rows_cap / 128) * 128);
    if (chunk > BTOT / 2) chunk = BTOT / 2;
    if (chunk < 128) chunk = 128;

    cast_x_kernel<<<dim3(BTOT * 256 / 1024), 256, 0, stream>>>(x, xb);
    cast_x_kernel<<<dim3(KTR * 65536 / 1024), 256, 0, stream>>>(Tw2, Tw2b);
    transpose_cast_kernel<<<dim3(64, KTR), 256, 0, stream>>>(Tw1, Tw1t, 256, 256);
    transpose_cast_kernel<<<dim3(64, 1),   256, 0, stream>>>(Ew1, Ew1t, 256, 256);
    transpose_cast_kernel<<<dim3(64, 1),   256, 0, stream>>>(Ew2, Ew2t, 256, 256);
    fuse_b_kernel<<<dim3(KTR), 256, 0, stream>>>(Tb2, Ew1, Eb1, bfb);
    fuse_w_kernel<<<dim3(4, KTR), 256, 0, stream>>>(Ew1t, Tw2b, Wft);

    for (int b0 = 0; b0 < BTOT; b0 += chunk) {
        int rows = (BTOT - b0 < chunk) ? (BTOT - b0) : chunk;
        chain_kernel<<<dim3((rows / 64) * NSLOT), 256, 0, stream>>>(
            xb, Tw1t, Tb1, Wft, bfb, Ew1t, Eb1, Ew2t, Eb2, zbuf, b0);
        reduce_kernel<<<dim3(rows / 32), 256, 0, stream>>>(zbuf, out, b0);
    }
}

// Round 7
// 873.837 us; speedup vs baseline: 1.0128x; 1.0128x over previous
//
#include <hip/hip_runtime.h>
#include <hip/hip_bf16.h>
#include <stdint.h>

#define BTOT  65536
#define KTR   11
#define NSLOT 12   // 11 transforms + z

typedef __attribute__((ext_vector_type(8))) short bf16x8_t;
typedef __attribute__((ext_vector_type(4))) float f32x4_t;

// Swizzled LDS layout: row m x 256 bf16 cols, 16B groups rotated by row so
// frag ds_read_b128 across 16 rows spreads banks (<=2-way, free per m136).
__device__ __forceinline__ int act_addr(int m, int n) {
    return m * 256 + ((((n >> 3) + m) & 31) << 3) + (n & 7);
}

// tanh-form gelu, exp2-native: log2(e) folded into the 1.59576912 constant.
__device__ __forceinline__ float gelu_fast(float x) {
    float x2 = x * x;
    float t2 = 2.3022083f * x * fmaf(0.044715f, x2, 1.0f);   // 1.5957691*log2e
    float e  = exp2f(fminf(t2, 44.f));
    return x * e * __builtin_amdgcn_rcpf(1.0f + e);
}

// generic fp32 -> bf16 cast, 4 elems/thread (also used for Tw2 cast)
__global__ void cast_x_kernel(const float* __restrict__ x, __hip_bfloat16* __restrict__ xb) {
    int i = (blockIdx.x * 256 + threadIdx.x) * 4;
    float4 v = *(const float4*)(x + i);
    union { __hip_bfloat16 h[4]; uint64_t u; } o;
    o.h[0] = __float2bfloat16(v.x);
    o.h[1] = __float2bfloat16(v.y);
    o.h[2] = __float2bfloat16(v.z);
    o.h[3] = __float2bfloat16(v.w);
    *(uint64_t*)(xb + i) = o.u;
}

// out[b][c][r] = in[b][r][c], cast fp32 -> bf16.
__global__ void transpose_cast_kernel(const float* __restrict__ in,
                                      __hip_bfloat16* __restrict__ out,
                                      int R, int C) {
    __shared__ float tile[32][33];
    int tpc = C >> 5;
    int tr = (blockIdx.x / tpc) << 5;
    int tc = (blockIdx.x % tpc) << 5;
    const float* bi = in + (size_t)blockIdx.y * R * C;
    __hip_bfloat16* bo = out + (size_t)blockIdx.y * R * C;
    int lx = threadIdx.x & 31, ly = threadIdx.x >> 5;
    #pragma unroll
    for (int r = 0; r < 32; r += 8)
        tile[ly + r][lx] = bi[(size_t)(tr + ly + r) * C + tc + lx];
    __syncthreads();
    #pragma unroll
    for (int r = 0; r < 32; r += 8)
        bo[(size_t)(tc + ly + r) * R + tr + lx] = __float2bfloat16(tile[lx][ly + r]);
}

// Fused weight: Wft[k][j][h] = sum_d Ew1t[j][d] * Tw2b[k][h][d]
// (= (Tw2[k] @ Ew1)^T). Legal: no nonlinearity between Tw2 and Ew1 stages.
__global__ void fuse_w_kernel(const __hip_bfloat16* __restrict__ Ew1t,
                              const __hip_bfloat16* __restrict__ Tw2b,
                              __hip_bfloat16* __restrict__ Wft)
{
    __shared__ __align__(16) __hip_bfloat16 bt[64 * 256];
    const int tid  = threadIdx.x;
    const int wave = tid >> 6, lane = tid & 63;
    const int lr = lane & 15, q = lane >> 4;
    const int k  = blockIdx.y;
    const int h0 = blockIdx.x << 6;
    const __hip_bfloat16* src = Tw2b + (size_t)k * 65536;

    #pragma unroll
    for (int i = 0; i < 8; ++i) {
        int lin = i * 256 + tid;
        int r = lin >> 5, g = lin & 31;
        bf16x8_t v = *(const bf16x8_t*)(src + (size_t)(h0 + r) * 256 + g * 8);
        *(bf16x8_t*)(bt + act_addr(r, g * 8)) = v;
    }
    __syncthreads();

    const int wc = wave << 6;
    f32x4_t acc[4][4];
    #pragma unroll
    for (int mt = 0; mt < 4; ++mt)
        #pragma unroll
        for (int nt = 0; nt < 4; ++nt)
            acc[mt][nt] = (f32x4_t){0.f, 0.f, 0.f, 0.f};

    #pragma unroll 1
    for (int kc = 0; kc < 8; ++kc) {
        const int kof = (kc << 5) + (q << 3);
        bf16x8_t a[4], b[4];
        #pragma unroll
        for (int mt = 0; mt < 4; ++mt)
            a[mt] = *(const bf16x8_t*)(Ew1t + (size_t)(wc + (mt << 4) + lr) * 256 + kof);
        #pragma unroll
        for (int nt = 0; nt < 4; ++nt)
            b[nt] = *(const bf16x8_t*)(bt + act_addr((nt << 4) + lr, kof));
        #pragma unroll
        for (int mt = 0; mt < 4; ++mt)
            #pragma unroll
            for (int nt = 0; nt < 4; ++nt)
                acc[mt][nt] = __builtin_amdgcn_mfma_f32_16x16x32_bf16(a[mt], b[nt], acc[mt][nt], 0, 0, 0);
    }

    __hip_bfloat16* dst = Wft + (size_t)k * 65536;
    #pragma unroll
    for (int mt = 0; mt < 4; ++mt)
        #pragma unroll
        for (int nt = 0; nt < 4; ++nt) {
            const int h = h0 + (nt << 4) + lr;
            #pragma unroll
            for (int r = 0; r < 4; ++r) {
                const int j = wc + (mt << 4) + (q << 2) + r;
                dst[(size_t)j * 256 + h] = __float2bfloat16(acc[mt][nt][r]);
            }
        }
}

// bf[k][j] = Eb1[j] + sum_d Tb2[k][d] * Ew1[d][j]   (fp32 throughout)
__global__ void fuse_b_kernel(const float* __restrict__ Tb2,
                              const float* __restrict__ Ew1,
                              const float* __restrict__ Eb1,
                              float* __restrict__ bf)
{
    const int k = blockIdx.x, j = threadIdx.x;
    float s = Eb1[j];
    #pragma unroll 4
    for (int d = 0; d < 256; ++d)
        s = fmaf(Tb2[k * 256 + d], Ew1[d * 256 + j], s);
    bf[k * 256 + j] = s;
}

// One stage: act[64][256] (LDS, swizzled) <- f(act @ W + bias).
// Bias folded into MFMA C-init; DO_GELU templated.
template<bool DO_GELU>
__device__ void run_stage(__hip_bfloat16* act,
                          const __hip_bfloat16* __restrict__ Wt,   // [n][k] row-major
                          const float* __restrict__ bias,
                          int wave, int lane)
{
    const int lr = lane & 15;
    const int q  = lane >> 4;
    const int wc = wave << 6;           // weight-col strip base

    f32x4_t acc[4][4];
    #pragma unroll
    for (int mt = 0; mt < 4; ++mt) {
        const float4 bv = *(const float4*)(bias + wc + (mt << 4) + (q << 2));
        #pragma unroll
        for (int nt = 0; nt < 4; ++nt)
            acc[mt][nt] = (f32x4_t){bv.x, bv.y, bv.z, bv.w};
    }

    bf16x8_t a[4];
    #pragma unroll
    for (int mt = 0; mt < 4; ++mt)
        a[mt] = *(const bf16x8_t*)(Wt + (size_t)(wc + (mt << 4) + lr) * 256 + (q << 3));

    #pragma unroll 1
    for (int kc = 0; kc < 8; ++kc) {
        const int kof = (kc << 5) + (q << 3);
        bf16x8_t an[4];
        if (kc < 7) {
            #pragma unroll
            for (int mt = 0; mt < 4; ++mt)
                an[mt] = *(const bf16x8_t*)(Wt + (size_t)(wc + (mt << 4) + lr) * 256 + kof + 32);
        }
        bf16x8_t b[4];
        #pragma unroll
        for (int nt = 0; nt < 4; ++nt)
            b[nt] = *(const bf16x8_t*)(act + act_addr((nt << 4) + lr, kof));
        #pragma unroll
        for (int mt = 0; mt < 4; ++mt)
            #pragma unroll
            for (int nt = 0; nt < 4; ++nt)
                acc[mt][nt] = __builtin_amdgcn_mfma_f32_16x16x32_bf16(a[mt], b[nt], acc[mt][nt], 0, 0, 0);
        if (kc < 7) {
            #pragma unroll
            for (int mt = 0; mt < 4; ++mt) a[mt] = an[mt];
        }
    }

    __syncthreads();   // all waves done reading act before overwrite
    #pragma unroll
    for (int mt = 0; mt < 4; ++mt) {
        const int nbase = wc + (mt << 4) + (q << 2);
        #pragma unroll
        for (int nt = 0; nt < 4; ++nt) {
            const int row = (nt << 4) + lr;
            union { __hip_bfloat16 h[4]; uint64_t u; } o;
            #pragma unroll
            for (int r = 0; r < 4; ++r) {
                float v = acc[mt][nt][r];
                if (DO_GELU) v = gelu_fast(v);
                o.h[r] = __float2bfloat16(v);
            }
            *(uint64_t*)(act + act_addr(row, nbase)) = o.u;
        }
    }
    __syncthreads();
}

// 2D slot-major grid (blockIdx.x=tile, blockIdx.y=slot): consecutive blocks
// share one weight panel (256KB, L2-hot across a whole tile sweep). R6's
// tile-major XCD swizzle REGRESSED 1.84x/row: it cycled all 24 weight
// matrices (5.6MB) per tile, thrashing the 4MB per-XCD L2. Weight-panel
// reuse dominates xb reuse (xb is L3-absorbed). Keep slot-major.
__launch_bounds__(256, 3)
__global__ void chain_kernel(const __hip_bfloat16* __restrict__ xb,
                             const __hip_bfloat16* __restrict__ Tw1t,
                             const float* __restrict__ Tb1,
                             const __hip_bfloat16* __restrict__ Wft,
                             const float* __restrict__ bfb,
                             const __hip_bfloat16* __restrict__ Ew1t,
                             const float* __restrict__ Eb1,
                             const __hip_bfloat16* __restrict__ Ew2t,
                             const float* __restrict__ Eb2,
                             __hip_bfloat16* __restrict__ zbuf,
                             int b0)
{
    __shared__ __align__(16) __hip_bfloat16 act[64 * 256];   // 32 KB
    const int tid  = threadIdx.x;
    const int wave = tid >> 6, lane = tid & 63;
    const int slot = blockIdx.y;
    const int tile = blockIdx.x;

    // stage x tile (64 rows) into LDS
    #pragma unroll
    for (int i = 0; i < 8; ++i) {
        int lin = i * 256 + tid;
        int r = lin >> 5, g = lin & 31;
        bf16x8_t v = *(const bf16x8_t*)(xb + (size_t)(b0 + tile * 64 + r) * 256 + g * 8);
        *(bf16x8_t*)(act + act_addr(r, g * 8)) = v;
    }
    __syncthreads();

    if (slot < KTR) {
        // T-slot: gelu(x@Tw1+b1) -> gelu(. @ Wf + bf) -> . @ Ew2 + e2
        run_stage<true>(act, Tw1t + (size_t)slot * 65536, Tb1 + slot * 256, wave, lane);
        run_stage<true>(act, Wft  + (size_t)slot * 65536, bfb + slot * 256, wave, lane);
    } else {
        // z-slot: gelu(x@Ew1+e1) -> . @ Ew2 + e2
        run_stage<true>(act, Ew1t, Eb1, wave, lane);
    }
    run_stage<false>(act, Ew2t, Eb2, wave, lane);

    // interleaved zbuf: [row][slot][256]
    __hip_bfloat16* dst = zbuf + ((size_t)(tile * 64) * NSLOT + slot) * 256;
    #pragma unroll
    for (int i = 0; i < 8; ++i) {
        int lin = i * 256 + tid;
        int r = lin >> 5, g = lin & 31;
        bf16x8_t v = *(const bf16x8_t*)(act + act_addr(r, g * 8));
        *(bf16x8_t*)(dst + (size_t)r * NSLOT * 256 + g * 8) = v;
    }
}

// Per row: G = Z Z^T (12x12 over H=256) via mfma(v,v,acc). Structure-bound
// investigations (R0/R3) proved reduce is memory-system-bound, not
// structure-bound: at chunk=65536 the 402MB zbuf spills the 256MB L3 and the
// chain->reduce round-trip costs ~450us of HBM writeback+refetch. Fixed by
// CHUNKING (zbuf/chunk stays L3-resident), not by kernel structure.
#define ROW_BODY(V, I)                                                        \
    {                                                                         \
        f32x4_t acc = (f32x4_t){0.f, 0.f, 0.f, 0.f};                          \
        _Pragma("unroll")                                                     \
        for (int kc = 0; kc < 8; ++kc)                                        \
            acc = __builtin_amdgcn_mfma_f32_16x16x32_bf16(V[kc], V[kc], acc, 0, 0, 0); \
        _Pragma("unroll")                                                     \
        for (int rr = 0; rr < 4; ++rr)                                        \
            Gw[wave][(q << 2) + rr][lr] = acc[rr];                            \
        float term = 0.f;                                                     \
        if (lane < 11) {                                                      \
            const int k = lane;                                               \
            float nr[NSLOT];                                                  \
            _Pragma("unroll")                                                 \
            for (int l = 0; l < NSLOT; ++l)                                   \
                nr[l] = __builtin_amdgcn_rcpf(fmaxf(sqrtf(Gw[wave][l][l]), 1e-4f)); \
            const float nrk = nr[k];                                          \
            float neg = 0.f;                                                  \
            _Pragma("unroll")                                                 \
            for (int l = 0; l < KTR; ++l)                                     \
                if (l != k)                                                   \
                    neg += __expf(Gw[wave][l][k] * nr[l] * nrk);              \
            float cz = Gw[wave][KTR][k] * nr[KTR] * nrk;                      \
            term = __logf(__expf(cz) + neg) - cz;                             \
        }                                                                     \
        term += __shfl_xor(term, 1);                                          \
        term += __shfl_xor(term, 2);                                          \
        term += __shfl_xor(term, 4);                                          \
        term += __shfl_xor(term, 8);                                          \
        if (lane == 0) out[b0 + r0 + (I)] = term;                             \
    }

__launch_bounds__(256, 4)
__global__ void reduce_kernel(const __hip_bfloat16* __restrict__ zbuf,
                              float* __restrict__ out, int b0)
{
    __shared__ float Gw[4][16][17];
    const int tid  = threadIdx.x;
    const int wave = tid >> 6, lane = tid & 63;
    const int lr = lane & 15, q = lane >> 4;
    const int slot = lr < NSLOT ? lr : NSLOT - 1;   // lanes 12-15 broadcast slot 11
    const size_t lanoff = (size_t)slot * 256 + (q << 3);

    const int r0 = (blockIdx.x * 4 + wave) * 8;     // 8 contiguous rows per wave
    const __hip_bfloat16* zr = zbuf + (size_t)r0 * (NSLOT * 256) + lanoff;

    bf16x8_t va[8], vb[8];
    #pragma unroll
    for (int kc = 0; kc < 8; ++kc)
        va[kc] = *(const bf16x8_t*)(zr + kc * 32);

    #pragma unroll 1
    for (int i2 = 0; i2 < 4; ++i2) {
        const int ie = i2 * 2;
        {   // even row: consume va, prefetch row ie+1 into vb (always valid)
            const __hip_bfloat16* zn = zr + (size_t)(ie + 1) * (NSLOT * 256);
            #pragma unroll
            for (int kc = 0; kc < 8; ++kc)
                vb[kc] = *(const bf16x8_t*)(zn + kc * 32);
            ROW_BODY(va, ie)
        }
        {   // odd row: consume vb, prefetch row ie+2 into va (guarded)
            if (ie + 2 < 8) {
                const __hip_bfloat16* zn = zr + (size_t)(ie + 2) * (NSLOT * 256);
                #pragma unroll
                for (int kc = 0; kc < 8; ++kc)
                    va[kc] = *(const bf16x8_t*)(zn + kc * 32);
            }
            ROW_BODY(vb, ie + 1)
        }
    }
}

extern "C" void kernel_launch(void* const* d_in, const int* in_sizes, int n_in,
                              void* d_out, int out_size, void* d_ws, size_t ws_size,
                              hipStream_t stream)
{
    const float* x   = (const float*)d_in[0];
    const float* Tw1 = (const float*)d_in[1];
    const float* Tb1 = (const float*)d_in[2];
    const float* Tw2 = (const float*)d_in[3];
    const float* Tb2 = (const float*)d_in[4];
    const float* Ew1 = (const float*)d_in[5];
    const float* Eb1 = (const float*)d_in[6];
    const float* Ew2 = (const float*)d_in[7];
    const float* Eb2 = (const float*)d_in[8];
    float* out = (float*)d_out;

    char* ws = (char*)d_ws;
    const size_t off_xb   = 0;
    const size_t off_tw1  = off_xb   + (size_t)BTOT * 256 * 2;     // 32 MB
    const size_t off_wf   = off_tw1  + (size_t)KTR * 65536 * 2;
    const size_t off_ew1  = off_wf   + (size_t)KTR * 65536 * 2;
    const size_t off_ew2  = off_ew1  + (size_t)65536 * 2;
    const size_t off_tw2b = off_ew2  + (size_t)65536 * 2;
    const size_t off_bf   = off_tw2b + (size_t)KTR * 65536 * 2;
    const size_t off_z    = off_bf   + (size_t)KTR * 256 * 4;

    __hip_bfloat16* xb   = (__hip_bfloat16*)(ws + off_xb);
    __hip_bfloat16* Tw1t = (__hip_bfloat16*)(ws + off_tw1);
    __hip_bfloat16* Wft  = (__hip_bfloat16*)(ws + off_wf);
    __hip_bfloat16* Ew1t = (__hip_bfloat16*)(ws + off_ew1);
    __hip_bfloat16* Ew2t = (__hip_bfloat16*)(ws + off_ew2);
    __hip_bfloat16* Tw2b = (__hip_bfloat16*)(ws + off_tw2b);
    float*          bfb  = (float*)(ws + off_bf);
    __hip_bfloat16* zbuf = (__hip_bfloat16*)(ws + off_z);

    // 4-chunk split: zbuf/chunk = 100MB (+xb 32MB +weights 6MB = ~140MB)
    // stays Infinity-Cache-resident, so the chain->reduce zbuf round-trip
    // never touches HBM. (R5: 1 chunk, zbuf 402MB > L3 -> ~450us hidden
    // writeback+refetch tax. R6: 2 chunks, 201MB, tax collapsed to ~120us.)
    long long zbytes = (long long)ws_size - (long long)off_z;
    long long rows_cap = zbytes > 0 ? zbytes / ((long long)NSLOT * 256 * 2) : 0;
    int chunk = (int)((rows_cap / 128) * 128);
    if (chunk > BTOT / 4) chunk = BTOT / 4;
    if (chunk < 128) chunk = 128;

    cast_x_kernel<<<dim3(BTOT * 256 / 1024), 256, 0, stream>>>(x, xb);
    cast_x_kernel<<<dim3(KTR * 65536 / 1024), 256, 0, stream>>>(Tw2, Tw2b);
    transpose_cast_kernel<<<dim3(64, KTR), 256, 0, stream>>>(Tw1, Tw1t, 256, 256);
    transpose_cast_kernel<<<dim3(64, 1),   256, 0, stream>>>(Ew1, Ew1t, 256, 256);
    transpose_cast_kernel<<<dim3(64, 1),   256, 0, stream>>>(Ew2, Ew2t, 256, 256);
    fuse_b_kernel<<<dim3(KTR), 256, 0, stream>>>(Tb2, Ew1, Eb1, bfb);
    fuse_w_kernel<<<dim3(4, KTR), 256, 0, stream>>>(Ew1t, Tw2b, Wft);

    for (int b0 = 0; b0 < BTOT; b0 += chunk) {
        int rows = (BTOT - b0 < chunk) ? (BTOT - b0) : chunk;
        chain_kernel<<<dim3(rows / 64, NSLOT), 256, 0, stream>>>(
            xb, Tw1t, Tb1, Wft, bfb, Ew1t, Eb1, Ew2t, Eb2, zbuf, b0);
        reduce_kernel<<<dim3(rows / 32), 256, 0, stream>>>(zbuf, out, b0);
    }
}

// Round 8
// 867.760 us; speedup vs baseline: 1.0199x; 1.0070x over previous
//
#include <hip/hip_runtime.h>
#include <hip/hip_bf16.h>
#include <stdint.h>

#define BTOT  65536
#define KTR   11
#define NSLOT 12   // 11 transforms + z

typedef __attribute__((ext_vector_type(8))) short bf16x8_t;
typedef __attribute__((ext_vector_type(4))) float f32x4_t;

// Swizzled LDS layout: row m x 256 bf16 cols, 16B groups rotated by row so
// frag ds_read_b128 across 16 rows spreads banks (<=2-way, free per m136).
__device__ __forceinline__ int act_addr(int m, int n) {
    return m * 256 + ((((n >> 3) + m) & 31) << 3) + (n & 7);
}

// tanh-form gelu, exp2-native: log2(e) folded into the 1.59576912 constant.
__device__ __forceinline__ float gelu_fast(float x) {
    float x2 = x * x;
    float t2 = 2.3022083f * x * fmaf(0.044715f, x2, 1.0f);   // 1.5957691*log2e
    float e  = exp2f(fminf(t2, 44.f));
    return x * e * __builtin_amdgcn_rcpf(1.0f + e);
}

// generic fp32 -> bf16 cast, 4 elems/thread (also used for Tw2 cast)
__global__ void cast_x_kernel(const float* __restrict__ x, __hip_bfloat16* __restrict__ xb) {
    int i = (blockIdx.x * 256 + threadIdx.x) * 4;
    float4 v = *(const float4*)(x + i);
    union { __hip_bfloat16 h[4]; uint64_t u; } o;
    o.h[0] = __float2bfloat16(v.x);
    o.h[1] = __float2bfloat16(v.y);
    o.h[2] = __float2bfloat16(v.z);
    o.h[3] = __float2bfloat16(v.w);
    *(uint64_t*)(xb + i) = o.u;
}

// out[b][c][r] = in[b][r][c], cast fp32 -> bf16.
__global__ void transpose_cast_kernel(const float* __restrict__ in,
                                      __hip_bfloat16* __restrict__ out,
                                      int R, int C) {
    __shared__ float tile[32][33];
    int tpc = C >> 5;
    int tr = (blockIdx.x / tpc) << 5;
    int tc = (blockIdx.x % tpc) << 5;
    const float* bi = in + (size_t)blockIdx.y * R * C;
    __hip_bfloat16* bo = out + (size_t)blockIdx.y * R * C;
    int lx = threadIdx.x & 31, ly = threadIdx.x >> 5;
    #pragma unroll
    for (int r = 0; r < 32; r += 8)
        tile[ly + r][lx] = bi[(size_t)(tr + ly + r) * C + tc + lx];
    __syncthreads();
    #pragma unroll
    for (int r = 0; r < 32; r += 8)
        bo[(size_t)(tc + ly + r) * R + tr + lx] = __float2bfloat16(tile[lx][ly + r]);
}

// Fused weight: Wft[k][j][h] = sum_d Ew1t[j][d] * Tw2b[k][h][d]
// (= (Tw2[k] @ Ew1)^T). Legal: no nonlinearity between Tw2 and Ew1 stages.
__global__ void fuse_w_kernel(const __hip_bfloat16* __restrict__ Ew1t,
                              const __hip_bfloat16* __restrict__ Tw2b,
                              __hip_bfloat16* __restrict__ Wft)
{
    __shared__ __align__(16) __hip_bfloat16 bt[64 * 256];
    const int tid  = threadIdx.x;
    const int wave = tid >> 6, lane = tid & 63;
    const int lr = lane & 15, q = lane >> 4;
    const int k  = blockIdx.y;
    const int h0 = blockIdx.x << 6;
    const __hip_bfloat16* src = Tw2b + (size_t)k * 65536;

    #pragma unroll
    for (int i = 0; i < 8; ++i) {
        int lin = i * 256 + tid;
        int r = lin >> 5, g = lin & 31;
        bf16x8_t v = *(const bf16x8_t*)(src + (size_t)(h0 + r) * 256 + g * 8);
        *(bf16x8_t*)(bt + act_addr(r, g * 8)) = v;
    }
    __syncthreads();

    const int wc = wave << 6;
    f32x4_t acc[4][4];
    #pragma unroll
    for (int mt = 0; mt < 4; ++mt)
        #pragma unroll
        for (int nt = 0; nt < 4; ++nt)
            acc[mt][nt] = (f32x4_t){0.f, 0.f, 0.f, 0.f};

    #pragma unroll 1
    for (int kc = 0; kc < 8; ++kc) {
        const int kof = (kc << 5) + (q << 3);
        bf16x8_t a[4], b[4];
        #pragma unroll
        for (int mt = 0; mt < 4; ++mt)
            a[mt] = *(const bf16x8_t*)(Ew1t + (size_t)(wc + (mt << 4) + lr) * 256 + kof);
        #pragma unroll
        for (int nt = 0; nt < 4; ++nt)
            b[nt] = *(const bf16x8_t*)(bt + act_addr((nt << 4) + lr, kof));
        #pragma unroll
        for (int mt = 0; mt < 4; ++mt)
            #pragma unroll
            for (int nt = 0; nt < 4; ++nt)
                acc[mt][nt] = __builtin_amdgcn_mfma_f32_16x16x32_bf16(a[mt], b[nt], acc[mt][nt], 0, 0, 0);
    }

    __hip_bfloat16* dst = Wft + (size_t)k * 65536;
    #pragma unroll
    for (int mt = 0; mt < 4; ++mt)
        #pragma unroll
        for (int nt = 0; nt < 4; ++nt) {
            const int h = h0 + (nt << 4) + lr;
            #pragma unroll
            for (int r = 0; r < 4; ++r) {
                const int j = wc + (mt << 4) + (q << 2) + r;
                dst[(size_t)j * 256 + h] = __float2bfloat16(acc[mt][nt][r]);
            }
        }
}

// bf[k][j] = Eb1[j] + sum_d Tb2[k][d] * Ew1[d][j]   (fp32 throughout)
__global__ void fuse_b_kernel(const float* __restrict__ Tb2,
                              const float* __restrict__ Ew1,
                              const float* __restrict__ Eb1,
                              float* __restrict__ bf)
{
    const int k = blockIdx.x, j = threadIdx.x;
    float s = Eb1[j];
    #pragma unroll 4
    for (int d = 0; d < 256; ++d)
        s = fmaf(Tb2[k * 256 + d], Ew1[d * 256 + j], s);
    bf[k * 256 + j] = s;
}

// One stage: act[64][256] (LDS, swizzled) <- f(act @ W + bias).
// Bias folded into MFMA C-init; DO_GELU templated.
template<bool DO_GELU>
__device__ void run_stage(__hip_bfloat16* act,
                          const __hip_bfloat16* __restrict__ Wt,   // [n][k] row-major
                          const float* __restrict__ bias,
                          int wave, int lane)
{
    const int lr = lane & 15;
    const int q  = lane >> 4;
    const int wc = wave << 6;           // weight-col strip base

    f32x4_t acc[4][4];
    #pragma unroll
    for (int mt = 0; mt < 4; ++mt) {
        const float4 bv = *(const float4*)(bias + wc + (mt << 4) + (q << 2));
        #pragma unroll
        for (int nt = 0; nt < 4; ++nt)
            acc[mt][nt] = (f32x4_t){bv.x, bv.y, bv.z, bv.w};
    }

    bf16x8_t a[4];
    #pragma unroll
    for (int mt = 0; mt < 4; ++mt)
        a[mt] = *(const bf16x8_t*)(Wt + (size_t)(wc + (mt << 4) + lr) * 256 + (q << 3));

    #pragma unroll 1
    for (int kc = 0; kc < 8; ++kc) {
        const int kof = (kc << 5) + (q << 3);
        bf16x8_t an[4];
        if (kc < 7) {
            #pragma unroll
            for (int mt = 0; mt < 4; ++mt)
                an[mt] = *(const bf16x8_t*)(Wt + (size_t)(wc + (mt << 4) + lr) * 256 + kof + 32);
        }
        bf16x8_t b[4];
        #pragma unroll
        for (int nt = 0; nt < 4; ++nt)
            b[nt] = *(const bf16x8_t*)(act + act_addr((nt << 4) + lr, kof));
        #pragma unroll
        for (int mt = 0; mt < 4; ++mt)
            #pragma unroll
            for (int nt = 0; nt < 4; ++nt)
                acc[mt][nt] = __builtin_amdgcn_mfma_f32_16x16x32_bf16(a[mt], b[nt], acc[mt][nt], 0, 0, 0);
        if (kc < 7) {
            #pragma unroll
            for (int mt = 0; mt < 4; ++mt) a[mt] = an[mt];
        }
    }

    __syncthreads();   // all waves done reading act before overwrite
    #pragma unroll
    for (int mt = 0; mt < 4; ++mt) {
        const int nbase = wc + (mt << 4) + (q << 2);
        #pragma unroll
        for (int nt = 0; nt < 4; ++nt) {
            const int row = (nt << 4) + lr;
            union { __hip_bfloat16 h[4]; uint64_t u; } o;
            #pragma unroll
            for (int r = 0; r < 4; ++r) {
                float v = acc[mt][nt][r];
                if (DO_GELU) v = gelu_fast(v);
                o.h[r] = __float2bfloat16(v);
            }
            *(uint64_t*)(act + act_addr(row, nbase)) = o.u;
        }
    }
    __syncthreads();
}

// Slot-major 2D grid (weight-panel L2 reuse; R6's tile-major swizzle
// regressed 1.84x by thrashing per-XCD L2 with all 24 weight matrices).
// EA-traffic law (5 rounds): chain dur ~= (FETCH+WRITE)/2.2 TB/s. This
// round attacks bytes: zbuf stored as CONTIGUOUS 32KB per-block blobs
// [tile][slot][64][256] (old interleaved [row][slot] scattered 512B chunks
// at 6144B stride -> WRITE_SIZE was 2.6x zbuf bytes), and zbuf stores are
// NONTEMPORAL (single-producer/single-consumer across dispatch boundary;
// keeps 100MB streams from evicting xb/weight panels in L2).
__launch_bounds__(256, 3)
__global__ void chain_kernel(const __hip_bfloat16* __restrict__ xb,
                             const __hip_bfloat16* __restrict__ Tw1t,
                             const float* __restrict__ Tb1,
                             const __hip_bfloat16* __restrict__ Wft,
                             const float* __restrict__ bfb,
                             const __hip_bfloat16* __restrict__ Ew1t,
                             const float* __restrict__ Eb1,
                             const __hip_bfloat16* __restrict__ Ew2t,
                             const float* __restrict__ Eb2,
                             __hip_bfloat16* __restrict__ zbuf,
                             int b0)
{
    __shared__ __align__(16) __hip_bfloat16 act[64 * 256];   // 32 KB
    const int tid  = threadIdx.x;
    const int wave = tid >> 6, lane = tid & 63;
    const int slot = blockIdx.y;
    const int tile = blockIdx.x;

    // stage x tile (64 rows) into LDS
    #pragma unroll
    for (int i = 0; i < 8; ++i) {
        int lin = i * 256 + tid;
        int r = lin >> 5, g = lin & 31;
        bf16x8_t v = *(const bf16x8_t*)(xb + (size_t)(b0 + tile * 64 + r) * 256 + g * 8);
        *(bf16x8_t*)(act + act_addr(r, g * 8)) = v;
    }
    __syncthreads();

    if (slot < KTR) {
        // T-slot: gelu(x@Tw1+b1) -> gelu(. @ Wf + bf) -> . @ Ew2 + e2
        run_stage<true>(act, Tw1t + (size_t)slot * 65536, Tb1 + slot * 256, wave, lane);
        run_stage<true>(act, Wft  + (size_t)slot * 65536, bfb + slot * 256, wave, lane);
    } else {
        // z-slot: gelu(x@Ew1+e1) -> . @ Ew2 + e2
        run_stage<true>(act, Ew1t, Eb1, wave, lane);
    }
    run_stage<false>(act, Ew2t, Eb2, wave, lane);

    // contiguous per-block zbuf blob: zbuf[tile][slot][64][256]
    __hip_bfloat16* dst = zbuf + (size_t)(tile * NSLOT + slot) * (64 * 256);
    #pragma unroll
    for (int i = 0; i < 8; ++i) {
        int lin = i * 256 + tid;                       // dst + lin*8 = [r=lin>>5][g*8]
        int r = lin >> 5, g = lin & 31;
        bf16x8_t v = *(const bf16x8_t*)(act + act_addr(r, g * 8));
        __builtin_nontemporal_store(v, (bf16x8_t*)(dst + lin * 8));
    }
}

// Per row: G = Z Z^T (12x12 over H=256) via mfma(v,v,acc). 8 rows/wave
// (never crossing a 64-row tile blob since 8|64), 2-deep row pipeline,
// rcp-for-divide tail. zbuf loads NONTEMPORAL (single-use stream).
// Addressing for blob layout: row i of slot s at
//   zbuf + tile*12*16384 + s*16384 + (rloc+i)*256.
#define ROW_BODY(V, I)                                                        \
    {                                                                         \
        f32x4_t acc = (f32x4_t){0.f, 0.f, 0.f, 0.f};                          \
        _Pragma("unroll")                                                     \
        for (int kc = 0; kc < 8; ++kc)                                        \
            acc = __builtin_amdgcn_mfma_f32_16x16x32_bf16(V[kc], V[kc], acc, 0, 0, 0); \
        _Pragma("unroll")                                                     \
        for (int rr = 0; rr < 4; ++rr)                                        \
            Gw[wave][(q << 2) + rr][lr] = acc[rr];                            \
        float term = 0.f;                                                     \
        if (lane < 11) {                                                      \
            const int k = lane;                                               \
            float nr[NSLOT];                                                  \
            _Pragma("unroll")                                                 \
            for (int l = 0; l < NSLOT; ++l)                                   \
                nr[l] = __builtin_amdgcn_rcpf(fmaxf(sqrtf(Gw[wave][l][l]), 1e-4f)); \
            const float nrk = nr[k];                                          \
            float neg = 0.f;                                                  \
            _Pragma("unroll")                                                 \
            for (int l = 0; l < KTR; ++l)                                     \
                if (l != k)                                                   \
                    neg += __expf(Gw[wave][l][k] * nr[l] * nrk);              \
            float cz = Gw[wave][KTR][k] * nr[KTR] * nrk;                      \
            term = __logf(__expf(cz) + neg) - cz;                             \
        }                                                                     \
        term += __shfl_xor(term, 1);                                          \
        term += __shfl_xor(term, 2);                                          \
        term += __shfl_xor(term, 4);                                          \
        term += __shfl_xor(term, 8);                                          \
        if (lane == 0) out[b0 + r0 + (I)] = term;                             \
    }

__launch_bounds__(256, 4)
__global__ void reduce_kernel(const __hip_bfloat16* __restrict__ zbuf,
                              float* __restrict__ out, int b0)
{
    __shared__ float Gw[4][16][17];
    const int tid  = threadIdx.x;
    const int wave = tid >> 6, lane = tid & 63;
    const int lr = lane & 15, q = lane >> 4;
    const int slot = lr < NSLOT ? lr : NSLOT - 1;   // lanes 12-15 broadcast slot 11

    const int r0   = (blockIdx.x * 4 + wave) * 8;   // 8 contiguous rows per wave
    const int tile = r0 >> 6, rloc = r0 & 63;       // all 8 rows inside one tile blob
    const __hip_bfloat16* zr = zbuf + (size_t)tile * (NSLOT * 64 * 256)
                             + (size_t)slot * (64 * 256) + rloc * 256 + (q << 3);

    bf16x8_t va[8], vb[8];
    #pragma unroll
    for (int kc = 0; kc < 8; ++kc)
        va[kc] = __builtin_nontemporal_load((const bf16x8_t*)(zr + kc * 32));

    #pragma unroll 1
    for (int i2 = 0; i2 < 4; ++i2) {
        const int ie = i2 * 2;
        {   // even row: consume va, prefetch row ie+1 into vb (always valid)
            const __hip_bfloat16* zn = zr + (ie + 1) * 256;
            #pragma unroll
            for (int kc = 0; kc < 8; ++kc)
                vb[kc] = __builtin_nontemporal_load((const bf16x8_t*)(zn + kc * 32));
            ROW_BODY(va, ie)
        }
        {   // odd row: consume vb, prefetch row ie+2 into va (guarded)
            if (ie + 2 < 8) {
                const __hip_bfloat16* zn = zr + (ie + 2) * 256;
                #pragma unroll
                for (int kc = 0; kc < 8; ++kc)
                    va[kc] = __builtin_nontemporal_load((const bf16x8_t*)(zn + kc * 32));
            }
            ROW_BODY(vb, ie + 1)
        }
    }
}

extern "C" void kernel_launch(void* const* d_in, const int* in_sizes, int n_in,
                              void* d_out, int out_size, void* d_ws, size_t ws_size,
                              hipStream_t stream)
{
    const float* x   = (const float*)d_in[0];
    const float* Tw1 = (const float*)d_in[1];
    const float* Tb1 = (const float*)d_in[2];
    const float* Tw2 = (const float*)d_in[3];
    const float* Tb2 = (const float*)d_in[4];
    const float* Ew1 = (const float*)d_in[5];
    const float* Eb1 = (const float*)d_in[6];
    const float* Ew2 = (const float*)d_in[7];
    const float* Eb2 = (const float*)d_in[8];
    float* out = (float*)d_out;

    char* ws = (char*)d_ws;
    const size_t off_xb   = 0;
    const size_t off_tw1  = off_xb   + (size_t)BTOT * 256 * 2;     // 32 MB
    const size_t off_wf   = off_tw1  + (size_t)KTR * 65536 * 2;
    const size_t off_ew1  = off_wf   + (size_t)KTR * 65536 * 2;
    const size_t off_ew2  = off_ew1  + (size_t)65536 * 2;
    const size_t off_tw2b = off_ew2  + (size_t)65536 * 2;
    const size_t off_bf   = off_tw2b + (size_t)KTR * 65536 * 2;
    const size_t off_z    = off_bf   + (size_t)KTR * 256 * 4;

    __hip_bfloat16* xb   = (__hip_bfloat16*)(ws + off_xb);
    __hip_bfloat16* Tw1t = (__hip_bfloat16*)(ws + off_tw1);
    __hip_bfloat16* Wft  = (__hip_bfloat16*)(ws + off_wf);
    __hip_bfloat16* Ew1t = (__hip_bfloat16*)(ws + off_ew1);
    __hip_bfloat16* Ew2t = (__hip_bfloat16*)(ws + off_ew2);
    __hip_bfloat16* Tw2b = (__hip_bfloat16*)(ws + off_tw2b);
    float*          bfb  = (float*)(ws + off_bf);
    __hip_bfloat16* zbuf = (__hip_bfloat16*)(ws + off_z);

    // 4-chunk split (zbuf/chunk = 100MB). Chunk count itself is
    // total-time-neutral (R5/R6/R7 invariance) -- kept at 4 so reduce's
    // zbuf reads stay L3-served while this round's byte-cut is measured.
    long long zbytes = (long long)ws_size - (long long)off_z;
    long long rows_cap = zbytes > 0 ? zbytes / ((long long)NSLOT * 256 * 2) : 0;
    int chunk = (int)((rows_cap / 128) * 128);
    if (chunk > BTOT / 4) chunk = BTOT / 4;
    if (chunk < 128) chunk = 128;

    cast_x_kernel<<<dim3(BTOT * 256 / 1024), 256, 0, stream>>>(x, xb);
    cast_x_kernel<<<dim3(KTR * 65536 / 1024), 256, 0, stream>>>(Tw2, Tw2b);
    transpose_cast_kernel<<<dim3(64, KTR), 256, 0, stream>>>(Tw1, Tw1t, 256, 256);
    transpose_cast_kernel<<<dim3(64, 1),   256, 0, stream>>>(Ew1, Ew1t, 256, 256);
    transpose_cast_kernel<<<dim3(64, 1),   256, 0, stream>>>(Ew2, Ew2t, 256, 256);
    fuse_b_kernel<<<dim3(KTR), 256, 0, stream>>>(Tb2, Ew1, Eb1, bfb);
    fuse_w_kernel<<<dim3(4, KTR), 256, 0, stream>>>(Ew1t, Tw2b, Wft);

    for (int b0 = 0; b0 < BTOT; b0 += chunk) {
        int rows = (BTOT - b0 < chunk) ? (BTOT - b0) : chunk;
        chain_kernel<<<dim3(rows / 64, NSLOT), 256, 0, stream>>>(
            xb, Tw1t, Tb1, Wft, bfb, Ew1t, Eb1, Ew2t, Eb2, zbuf, b0);
        reduce_kernel<<<dim3(rows / 32), 256, 0, stream>>>(zbuf, out, b0);
    }
}

// Round 9
// 838.408 us; speedup vs baseline: 1.0556x; 1.0350x over previous
//
#include <hip/hip_runtime.h>
#include <hip/hip_bf16.h>
#include <stdint.h>

#define BTOT  65536
#define KTR   11
#define NSLOT 12   // 11 transforms + z

typedef __attribute__((ext_vector_type(8))) short bf16x8_t;
typedef __attribute__((ext_vector_type(4))) float f32x4_t;

// Swizzled LDS layout: row m x 256 bf16 cols, 16B groups rotated by row so
// frag ds_read_b128 across 16 rows spreads banks (<=2-way, free per m136).
__device__ __forceinline__ int act_addr(int m, int n) {
    return m * 256 + ((((n >> 3) + m) & 31) << 3) + (n & 7);
}

// tanh-form gelu via sigmoid identity: gelu = x * sigma(t2/log2e) =
// x * rcp(1 + 2^-t2). No clamp needed: t2->+inf => e=0 => x; t2->-inf =>
// e=inf => rcp=0 => 0. Two fewer VALU ops than the e/(1+e) form.
__device__ __forceinline__ float gelu_fast(float x) {
    float x2 = x * x;
    float t2 = 2.3022083f * x * fmaf(0.044715f, x2, 1.0f);   // 1.5957691*log2e
    float e  = exp2f(-t2);
    return x * __builtin_amdgcn_rcpf(1.0f + e);
}

// generic fp32 -> bf16 cast, 4 elems/thread (also used for Tw2 cast)
__global__ void cast_x_kernel(const float* __restrict__ x, __hip_bfloat16* __restrict__ xb) {
    int i = (blockIdx.x * 256 + threadIdx.x) * 4;
    float4 v = *(const float4*)(x + i);
    union { __hip_bfloat16 h[4]; uint64_t u; } o;
    o.h[0] = __float2bfloat16(v.x);
    o.h[1] = __float2bfloat16(v.y);
    o.h[2] = __float2bfloat16(v.z);
    o.h[3] = __float2bfloat16(v.w);
    *(uint64_t*)(xb + i) = o.u;
}

// out[b][c][r] = in[b][r][c], cast fp32 -> bf16.
__global__ void transpose_cast_kernel(const float* __restrict__ in,
                                      __hip_bfloat16* __restrict__ out,
                                      int R, int C) {
    __shared__ float tile[32][33];
    int tpc = C >> 5;
    int tr = (blockIdx.x / tpc) << 5;
    int tc = (blockIdx.x % tpc) << 5;
    const float* bi = in + (size_t)blockIdx.y * R * C;
    __hip_bfloat16* bo = out + (size_t)blockIdx.y * R * C;
    int lx = threadIdx.x & 31, ly = threadIdx.x >> 5;
    #pragma unroll
    for (int r = 0; r < 32; r += 8)
        tile[ly + r][lx] = bi[(size_t)(tr + ly + r) * C + tc + lx];
    __syncthreads();
    #pragma unroll
    for (int r = 0; r < 32; r += 8)
        bo[(size_t)(tc + ly + r) * R + tr + lx] = __float2bfloat16(tile[lx][ly + r]);
}

// Fused weight: Wft[k][j][h] = sum_d Ew1t[j][d] * Tw2b[k][h][d]
// (= (Tw2[k] @ Ew1)^T). Legal: no nonlinearity between Tw2 and Ew1 stages.
__global__ void fuse_w_kernel(const __hip_bfloat16* __restrict__ Ew1t,
                              const __hip_bfloat16* __restrict__ Tw2b,
                              __hip_bfloat16* __restrict__ Wft)
{
    __shared__ __align__(16) __hip_bfloat16 bt[64 * 256];
    const int tid  = threadIdx.x;
    const int wave = tid >> 6, lane = tid & 63;
    const int lr = lane & 15, q = lane >> 4;
    const int k  = blockIdx.y;
    const int h0 = blockIdx.x << 6;
    const __hip_bfloat16* src = Tw2b + (size_t)k * 65536;

    #pragma unroll
    for (int i = 0; i < 8; ++i) {
        int lin = i * 256 + tid;
        int r = lin >> 5, g = lin & 31;
        bf16x8_t v = *(const bf16x8_t*)(src + (size_t)(h0 + r) * 256 + g * 8);
        *(bf16x8_t*)(bt + act_addr(r, g * 8)) = v;
    }
    __syncthreads();

    const int wc = wave << 6;
    f32x4_t acc[4][4];
    #pragma unroll
    for (int mt = 0; mt < 4; ++mt)
        #pragma unroll
        for (int nt = 0; nt < 4; ++nt)
            acc[mt][nt] = (f32x4_t){0.f, 0.f, 0.f, 0.f};

    #pragma unroll 1
    for (int kc = 0; kc < 8; ++kc) {
        const int kof = (kc << 5) + (q << 3);
        bf16x8_t a[4], b[4];
        #pragma unroll
        for (int mt = 0; mt < 4; ++mt)
            a[mt] = *(const bf16x8_t*)(Ew1t + (size_t)(wc + (mt << 4) + lr) * 256 + kof);
        #pragma unroll
        for (int nt = 0; nt < 4; ++nt)
            b[nt] = *(const bf16x8_t*)(bt + act_addr((nt << 4) + lr, kof));
        #pragma unroll
        for (int mt = 0; mt < 4; ++mt)
            #pragma unroll
            for (int nt = 0; nt < 4; ++nt)
                acc[mt][nt] = __builtin_amdgcn_mfma_f32_16x16x32_bf16(a[mt], b[nt], acc[mt][nt], 0, 0, 0);
    }

    __hip_bfloat16* dst = Wft + (size_t)k * 65536;
    #pragma unroll
    for (int mt = 0; mt < 4; ++mt)
        #pragma unroll
        for (int nt = 0; nt < 4; ++nt) {
            const int h = h0 + (nt << 4) + lr;
            #pragma unroll
            for (int r = 0; r < 4; ++r) {
                const int j = wc + (mt << 4) + (q << 2) + r;
                dst[(size_t)j * 256 + h] = __float2bfloat16(acc[mt][nt][r]);
            }
        }
}

// bf[k][j] = Eb1[j] + sum_d Tb2[k][d] * Ew1[d][j]   (fp32 throughout)
__global__ void fuse_b_kernel(const float* __restrict__ Tb2,
                              const float* __restrict__ Ew1,
                              const float* __restrict__ Eb1,
                              float* __restrict__ bf)
{
    const int k = blockIdx.x, j = threadIdx.x;
    float s = Eb1[j];
    #pragma unroll 4
    for (int d = 0; d < 256; ++d)
        s = fmaf(Tb2[k * 256 + d], Ew1[d * 256 + j], s);
    bf[k * 256 + j] = s;
}

// MFMA half of a stage: acc <- bias; acc += W^T x act^T over K=256.
__device__ __forceinline__ void mfma_part(const __hip_bfloat16* act,
                                          const __hip_bfloat16* __restrict__ Wt,
                                          const float* __restrict__ bias,
                                          f32x4_t acc[4][4], int lr, int q, int wc)
{
    #pragma unroll
    for (int mt = 0; mt < 4; ++mt) {
        const float4 bv = *(const float4*)(bias + wc + (mt << 4) + (q << 2));
        #pragma unroll
        for (int nt = 0; nt < 4; ++nt)
            acc[mt][nt] = (f32x4_t){bv.x, bv.y, bv.z, bv.w};
    }
    #pragma unroll 1
    for (int kc = 0; kc < 8; ++kc) {
        const int kof = (kc << 5) + (q << 3);
        bf16x8_t a[4], b[4];
        #pragma unroll
        for (int mt = 0; mt < 4; ++mt)
            a[mt] = *(const bf16x8_t*)(Wt + (size_t)(wc + (mt << 4) + lr) * 256 + kof);
        #pragma unroll
        for (int nt = 0; nt < 4; ++nt)
            b[nt] = *(const bf16x8_t*)(act + act_addr((nt << 4) + lr, kof));
        #pragma unroll
        for (int mt = 0; mt < 4; ++mt)
            #pragma unroll
            for (int nt = 0; nt < 4; ++nt)
                acc[mt][nt] = __builtin_amdgcn_mfma_f32_16x16x32_bf16(a[mt], b[nt], acc[mt][nt], 0, 0, 0);
    }
}

// Epilogue half: gelu/cvt/swizzled ds_write of the 64 outputs.
template<bool DO_GELU>
__device__ __forceinline__ void ep_part(__hip_bfloat16* act, f32x4_t acc[4][4],
                                        int lr, int q, int wc)
{
    #pragma unroll
    for (int mt = 0; mt < 4; ++mt) {
        const int nbase = wc + (mt << 4) + (q << 2);
        #pragma unroll
        for (int nt = 0; nt < 4; ++nt) {
            const int row = (nt << 4) + lr;
            union { __hip_bfloat16 h[4]; uint64_t u; } o;
            #pragma unroll
            for (int r = 0; r < 4; ++r) {
                float v = acc[mt][nt][r];
                if (DO_GELU) v = gelu_fast(v);
                o.h[r] = __float2bfloat16(v);
            }
            *(uint64_t*)(act + act_addr(row, nbase)) = o.u;
        }
    }
}

// Paired-slot software-pipelined chain: one block owns TWO slots (s0,s1) of
// one tile, two act buffers. Phases offset by half a stage so each phase
// co-issues mfma(one slot) with epilogue(other slot) -- matrix and VALU
// pipes overlap WITHIN a wave instead of only across blocks. 7 barriers per
// 6 stages vs 12 in the serial form. R8 baseline was epilogue-serialization
// bound: MfmaUtil 17.5 / VALUBusy 42 with both pipes idling alternately.
// Slot-pair grid keeps blockIdx.x=tile-major-within-pair (weight panels for
// the pair stay L2-hot across the tile sweep, as slot-major did).
__launch_bounds__(256, 2)
__global__ void chain_kernel(const __hip_bfloat16* __restrict__ xb,
                             const __hip_bfloat16* __restrict__ Tw1t,
                             const float* __restrict__ Tb1,
                             const __hip_bfloat16* __restrict__ Wft,
                             const float* __restrict__ bfb,
                             const __hip_bfloat16* __restrict__ Ew1t,
                             const float* __restrict__ Eb1,
                             const __hip_bfloat16* __restrict__ Ew2t,
                             const float* __restrict__ Eb2,
                             __hip_bfloat16* __restrict__ zbuf,
                             int b0)
{
    __shared__ __align__(16) __hip_bfloat16 actA[64 * 256];   // 32 KB
    __shared__ __align__(16) __hip_bfloat16 actB[64 * 256];   // 32 KB
    const int tid  = threadIdx.x;
    const int wave = tid >> 6, lane = tid & 63;
    const int lr = lane & 15, q = lane >> 4, wc = wave << 6;
    const int pair = blockIdx.y;
    const int tile = blockIdx.x;
    const int s0 = pair * 2, s1 = s0 + 1;
    const bool zp = (pair == 5);          // s1 == 11 is the z (encoder) slot

    // stage x tile into BOTH buffers
    #pragma unroll
    for (int i = 0; i < 8; ++i) {
        int lin = i * 256 + tid;
        int r = lin >> 5, g = lin & 31;
        bf16x8_t v = *(const bf16x8_t*)(xb + (size_t)(b0 + tile * 64 + r) * 256 + g * 8);
        *(bf16x8_t*)(actA + act_addr(r, g * 8)) = v;
        *(bf16x8_t*)(actB + act_addr(r, g * 8)) = v;
    }
    __syncthreads();

    // stage tables: A = slot s0 (always a T-slot), B = slot s1 (T or z)
    const __hip_bfloat16* WA0 = Tw1t + (size_t)s0 * 65536;
    const __hip_bfloat16* WA1 = Wft  + (size_t)s0 * 65536;
    const float* BA0 = Tb1 + s0 * 256;
    const float* BA1 = bfb + s0 * 256;
    const __hip_bfloat16* WB0 = zp ? Ew1t : Tw1t + (size_t)s1 * 65536;
    const __hip_bfloat16* WB1 = zp ? Ew2t : Wft  + (size_t)s1 * 65536;
    const float* BB0 = zp ? Eb1 : Tb1 + s1 * 256;
    const float* BB1 = zp ? Eb2 : bfb + s1 * 256;

    f32x4_t accA[4][4], accB[4][4];

    // ph0: warm A
    mfma_part(actA, WA0, BA0, accA, lr, q, wc);
    __syncthreads();
    // ph1: mfma B0 || ep A0 (gelu)
    mfma_part(actB, WB0, BB0, accB, lr, q, wc);
    ep_part<true>(actA, accA, lr, q, wc);
    __syncthreads();
    // ph2: mfma A1 || ep B0 (gelu for both T and z first stages)
    mfma_part(actA, WA1, BA1, accA, lr, q, wc);
    ep_part<true>(actB, accB, lr, q, wc);
    __syncthreads();
    // ph3: mfma B1 || ep A1 (gelu)
    mfma_part(actB, WB1, BB1, accB, lr, q, wc);
    ep_part<true>(actA, accA, lr, q, wc);
    __syncthreads();
    // ph4: mfma A2 (Ew2) || ep B1 (T: gelu; z: final, no gelu)
    mfma_part(actA, Ew2t, Eb2, accA, lr, q, wc);
    if (zp) ep_part<false>(actB, accB, lr, q, wc);
    else    ep_part<true >(actB, accB, lr, q, wc);
    __syncthreads();
    // ph5: (T-pair) mfma B2 (Ew2) || ep A2 (no gelu)
    if (!zp) mfma_part(actB, Ew2t, Eb2, accB, lr, q, wc);
    ep_part<false>(actA, accA, lr, q, wc);
    __syncthreads();
    // ph6: (T-pair) ep B2 (no gelu)
    if (!zp) {
        ep_part<false>(actB, accB, lr, q, wc);
        __syncthreads();
    }

    // contiguous per-slot zbuf blobs: zbuf[tile][slot][64][256], nontemporal
    __hip_bfloat16* d0 = zbuf + (size_t)(tile * NSLOT + s0) * (64 * 256);
    __hip_bfloat16* d1 = zbuf + (size_t)(tile * NSLOT + s1) * (64 * 256);
    #pragma unroll
    for (int i = 0; i < 8; ++i) {
        int lin = i * 256 + tid;
        int r = lin >> 5, g = lin & 31;
        bf16x8_t v0 = *(const bf16x8_t*)(actA + act_addr(r, g * 8));
        __builtin_nontemporal_store(v0, (bf16x8_t*)(d0 + lin * 8));
        bf16x8_t v1 = *(const bf16x8_t*)(actB + act_addr(r, g * 8));
        __builtin_nontemporal_store(v1, (bf16x8_t*)(d1 + lin * 8));
    }
}

// Per row: G = Z Z^T (12x12 over H=256) via mfma(v,v,acc). 8 rows/wave,
// 2-deep row pipeline, rcp-for-divide tail, nontemporal blob reads.
// Byte-identical to R8.
#define ROW_BODY(V, I)                                                        \
    {                                                                         \
        f32x4_t acc = (f32x4_t){0.f, 0.f, 0.f, 0.f};                          \
        _Pragma("unroll")                                                     \
        for (int kc = 0; kc < 8; ++kc)                                        \
            acc = __builtin_amdgcn_mfma_f32_16x16x32_bf16(V[kc], V[kc], acc, 0, 0, 0); \
        _Pragma("unroll")                                                     \
        for (int rr = 0; rr < 4; ++rr)                                        \
            Gw[wave][(q << 2) + rr][lr] = acc[rr];                            \
        float term = 0.f;                                                     \
        if (lane < 11) {                                                      \
            const int k = lane;                                               \
            float nr[NSLOT];                                                  \
            _Pragma("unroll")                                                 \
            for (int l = 0; l < NSLOT; ++l)                                   \
                nr[l] = __builtin_amdgcn_rcpf(fmaxf(sqrtf(Gw[wave][l][l]), 1e-4f)); \
            const float nrk = nr[k];                                          \
            float neg = 0.f;                                                  \
            _Pragma("unroll")                                                 \
            for (int l = 0; l < KTR; ++l)                                     \
                if (l != k)                                                   \
                    neg += __expf(Gw[wave][l][k] * nr[l] * nrk);              \
            float cz = Gw[wave][KTR][k] * nr[KTR] * nrk;                      \
            term = __logf(__expf(cz) + neg) - cz;                             \
        }                                                                     \
        term += __shfl_xor(term, 1);                                          \
        term += __shfl_xor(term, 2);                                          \
        term += __shfl_xor(term, 4);                                          \
        term += __shfl_xor(term, 8);                                          \
        if (lane == 0) out[b0 + r0 + (I)] = term;                             \
    }

__launch_bounds__(256, 4)
__global__ void reduce_kernel(const __hip_bfloat16* __restrict__ zbuf,
                              float* __restrict__ out, int b0)
{
    __shared__ float Gw[4][16][17];
    const int tid  = threadIdx.x;
    const int wave = tid >> 6, lane = tid & 63;
    const int lr = lane & 15, q = lane >> 4;
    const int slot = lr < NSLOT ? lr : NSLOT - 1;   // lanes 12-15 broadcast slot 11

    const int r0   = (blockIdx.x * 4 + wave) * 8;   // 8 contiguous rows per wave
    const int tile = r0 >> 6, rloc = r0 & 63;       // all 8 rows inside one tile blob
    const __hip_bfloat16* zr = zbuf + (size_t)tile * (NSLOT * 64 * 256)
                             + (size_t)slot * (64 * 256) + rloc * 256 + (q << 3);

    bf16x8_t va[8], vb[8];
    #pragma unroll
    for (int kc = 0; kc < 8; ++kc)
        va[kc] = __builtin_nontemporal_load((const bf16x8_t*)(zr + kc * 32));

    #pragma unroll 1
    for (int i2 = 0; i2 < 4; ++i2) {
        const int ie = i2 * 2;
        {   // even row: consume va, prefetch row ie+1 into vb (always valid)
            const __hip_bfloat16* zn = zr + (ie + 1) * 256;
            #pragma unroll
            for (int kc = 0; kc < 8; ++kc)
                vb[kc] = __builtin_nontemporal_load((const bf16x8_t*)(zn + kc * 32));
            ROW_BODY(va, ie)
        }
        {   // odd row: consume vb, prefetch row ie+2 into va (guarded)
            if (ie + 2 < 8) {
                const __hip_bfloat16* zn = zr + (ie + 2) * 256;
                #pragma unroll
                for (int kc = 0; kc < 8; ++kc)
                    va[kc] = __builtin_nontemporal_load((const bf16x8_t*)(zn + kc * 32));
            }
            ROW_BODY(vb, ie + 1)
        }
    }
}

extern "C" void kernel_launch(void* const* d_in, const int* in_sizes, int n_in,
                              void* d_out, int out_size, void* d_ws, size_t ws_size,
                              hipStream_t stream)
{
    const float* x   = (const float*)d_in[0];
    const float* Tw1 = (const float*)d_in[1];
    const float* Tb1 = (const float*)d_in[2];
    const float* Tw2 = (const float*)d_in[3];
    const float* Tb2 = (const float*)d_in[4];
    const float* Ew1 = (const float*)d_in[5];
    const float* Eb1 = (const float*)d_in[6];
    const float* Ew2 = (const float*)d_in[7];
    const float* Eb2 = (const float*)d_in[8];
    float* out = (float*)d_out;

    char* ws = (char*)d_ws;
    const size_t off_xb   = 0;
    const size_t off_tw1  = off_xb   + (size_t)BTOT * 256 * 2;     // 32 MB
    const size_t off_wf   = off_tw1  + (size_t)KTR * 65536 * 2;
    const size_t off_ew1  = off_wf   + (size_t)KTR * 65536 * 2;
    const size_t off_ew2  = off_ew1  + (size_t)65536 * 2;
    const size_t off_tw2b = off_ew2  + (size_t)65536 * 2;
    const size_t off_bf   = off_tw2b + (size_t)KTR * 65536 * 2;
    const size_t off_z    = off_bf   + (size_t)KTR * 256 * 4;

    __hip_bfloat16* xb   = (__hip_bfloat16*)(ws + off_xb);
    __hip_bfloat16* Tw1t = (__hip_bfloat16*)(ws + off_tw1);
    __hip_bfloat16* Wft  = (__hip_bfloat16*)(ws + off_wf);
    __hip_bfloat16* Ew1t = (__hip_bfloat16*)(ws + off_ew1);
    __hip_bfloat16* Ew2t = (__hip_bfloat16*)(ws + off_ew2);
    __hip_bfloat16* Tw2b = (__hip_bfloat16*)(ws + off_tw2b);
    float*          bfb  = (float*)(ws + off_bf);
    __hip_bfloat16* zbuf = (__hip_bfloat16*)(ws + off_z);

    // 4-chunk split (zbuf/chunk = 100MB, L3-resident for the reduce reads).
    long long zbytes = (long long)ws_size - (long long)off_z;
    long long rows_cap = zbytes > 0 ? zbytes / ((long long)NSLOT * 256 * 2) : 0;
    int chunk = (int)((rows_cap / 128) * 128);
    if (chunk > BTOT / 4) chunk = BTOT / 4;
    if (chunk < 128) chunk = 128;

    cast_x_kernel<<<dim3(BTOT * 256 / 1024), 256, 0, stream>>>(x, xb);
    cast_x_kernel<<<dim3(KTR * 65536 / 1024), 256, 0, stream>>>(Tw2, Tw2b);
    transpose_cast_kernel<<<dim3(64, KTR), 256, 0, stream>>>(Tw1, Tw1t, 256, 256);
    transpose_cast_kernel<<<dim3(64, 1),   256, 0, stream>>>(Ew1, Ew1t, 256, 256);
    transpose_cast_kernel<<<dim3(64, 1),   256, 0, stream>>>(Ew2, Ew2t, 256, 256);
    fuse_b_kernel<<<dim3(KTR), 256, 0, stream>>>(Tb2, Ew1, Eb1, bfb);
    fuse_w_kernel<<<dim3(4, KTR), 256, 0, stream>>>(Ew1t, Tw2b, Wft);

    for (int b0 = 0; b0 < BTOT; b0 += chunk) {
        int rows = (BTOT - b0 < chunk) ? (BTOT - b0) : chunk;
        chain_kernel<<<dim3(rows / 64, NSLOT / 2), 256, 0, stream>>>(
            xb, Tw1t, Tb1, Wft, bfb, Ew1t, Eb1, Ew2t, Eb2, zbuf, b0);
        reduce_kernel<<<dim3(rows / 32), 256, 0, stream>>>(zbuf, out, b0);
    }
}